// Round 3
// baseline (922.290 us; speedup 1.0000x reference)
//
#include <hip/hip_runtime.h>
#include <math.h>
#include <stdint.h>

namespace {
constexpr float kDT  = 0.01f;   // DT / SUBSTEP, SUBSTEP == 1
constexpr int   kIter = 10;
constexpr float kH   = -2.0f;
constexpr float kEps = 1e-5f;
constexpr int   kB = 8;
constexpr int   kN = 50000;
constexpr int   kE = 200000;
constexpr int   kBN = kB * kN;
constexpr int   kBE = kB * kE;
constexpr int   kNB = (kN + 255) / 256;   // 196 blocks for per-vertex scan
}

// ---------------- CSR build (once per launch) ----------------

__global__ void count_kernel(const int* __restrict__ Cdist, int* __restrict__ counts) {
    int e = blockIdx.x * blockDim.x + threadIdx.x;
    if (e >= kE) return;
    atomicAdd(&counts[Cdist[2 * e + 0]], 1);
    atomicAdd(&counts[Cdist[2 * e + 1]], 1);
}

// Multi-block exclusive scan of counts[0..kN) -> start[0..kN].
__global__ void partial_sum_kernel(const int* __restrict__ counts, int* __restrict__ blkSum) {
    __shared__ int s[256];
    int i = blockIdx.x * 256 + threadIdx.x;
    s[threadIdx.x] = (i < kN) ? counts[i] : 0;
    __syncthreads();
    for (int off = 128; off > 0; off >>= 1) {
        if (threadIdx.x < off) s[threadIdx.x] += s[threadIdx.x + off];
        __syncthreads();
    }
    if (threadIdx.x == 0) blkSum[blockIdx.x] = s[0];
}

__global__ void scan_sums_kernel(const int* __restrict__ blkSum, int* __restrict__ blkOff) {
    __shared__ int s[kNB];
    int tid = threadIdx.x;                 // 256 threads
    if (tid < kNB) s[tid] = blkSum[tid];
    __syncthreads();
    if (tid == 0) {
        int acc = 0;
        for (int i = 0; i < kNB; ++i) { int v = s[i]; s[i] = acc; acc += v; }
    }
    __syncthreads();
    if (tid < kNB) blkOff[tid] = s[tid];
}

__global__ void scatter_scan_kernel(const int* __restrict__ counts,
                                    const int* __restrict__ blkOff,
                                    int* __restrict__ start) {
    __shared__ int s[256];
    int tid = threadIdx.x;
    int i = blockIdx.x * 256 + tid;
    int c = (i < kN) ? counts[i] : 0;
    s[tid] = c;
    __syncthreads();
    for (int off = 1; off < 256; off <<= 1) {      // inclusive Hillis-Steele
        int v = (tid >= off) ? s[tid - off] : 0;
        __syncthreads();
        s[tid] += v;
        __syncthreads();
    }
    int incl = s[tid];
    int excl = incl - c;
    if (i < kN) start[i] = blkOff[blockIdx.x] + excl;
    if (i == kN - 1) start[kN] = blkOff[blockIdx.x] + incl;   // == 2E
}

// inc id = 2*e + side (side 0: i endpoint, +; side 1: j endpoint, -)
// Fill order is nondeterministic (atomics); summation-order FP wiggle is far
// below the 2% tolerance (R1's fully-atomic version passed).
__global__ void fill_kernel(const int* __restrict__ Cdist, int* __restrict__ cursor,
                            int* __restrict__ inc) {
    int e = blockIdx.x * blockDim.x + threadIdx.x;
    if (e >= kE) return;
    int vi = Cdist[2 * e + 0];
    int vj = Cdist[2 * e + 1];
    int p0 = atomicAdd(&cursor[vi], 1);
    inc[p0] = 2 * e;
    int p1 = atomicAdd(&cursor[vj], 1);
    inc[p1] = 2 * e + 1;
}

// slot position of each edge endpoint in the CSR slot array
__global__ void invert_kernel(const int* __restrict__ inc,
                              int* __restrict__ slotI, int* __restrict__ slotJ) {
    int k = blockIdx.x * blockDim.x + threadIdx.x;
    if (k >= 2 * kE) return;
    int ic = inc[k];
    int e = ic >> 1;
    if (ic & 1) slotJ[e] = k; else slotI[e] = k;
}

// ---------------- per-edge constants ----------------

__global__ void ec_kernel(const int* __restrict__ Cdist, const float* __restrict__ Cinit,
                          int4* __restrict__ EC) {
    int e = blockIdx.x * blockDim.x + threadIdx.x;
    if (e >= kE) return;
    EC[e] = make_int4(Cdist[2 * e + 0], Cdist[2 * e + 1], __float_as_int(Cinit[e]), 0);
}

// Per (b,e): A = (comp_i+comp_j)/2, rSA = 1/(S + A) with S==0 -> inf.
__global__ void precompute_kernel(const int* __restrict__ Cdist,
                                  const float* __restrict__ Vw,
                                  const float* __restrict__ Vcomp,
                                  float2* __restrict__ AS) {
    int b = blockIdx.x & 7;
    int e = (blockIdx.x >> 3) * blockDim.x + threadIdx.x;
    if (e >= kE) return;
    int vi = Cdist[2 * e + 0];
    int vj = Cdist[2 * e + 1];
    size_t base = (size_t)b * kN;
    float A = (Vcomp[base + vi] + Vcomp[base + vj]) * 0.5f;
    float S = Vw[base + vi] + Vw[base + vj];
    if (S == 0.0f) S = INFINITY;
    AS[(size_t)b * kE + e] = make_float2(A, 1.0f / (S + A));
}

// ---------------- physics ----------------

__global__ void predict_kernel(const float* __restrict__ V,
                               const float* __restrict__ Vvel,
                               const float* __restrict__ Vmass,
                               const float* __restrict__ Vforce,
                               float* __restrict__ Vp) {
    int idx = blockIdx.x * blockDim.x + threadIdx.x;
    if (idx >= kBN) return;
    float m = Vmass[idx];
#pragma unroll
    for (int c = 0; c < 3; ++c) {
        int k = idx * 3 + c;
        float vel_pred = Vvel[k] + (kDT * Vforce[k]) / m;  // (dt*F)/m, reference order
        Vp[k] = V[k] + kDT * vel_pred;
    }
}

// Slot path phase 1: per-constraint correction, written into both CSR slots.
__global__ void solve_slot_kernel(const float* __restrict__ Vp,
                                  float* __restrict__ L,
                                  const float2* __restrict__ AS,
                                  const int4* __restrict__ EC,
                                  const int* __restrict__ slotI,
                                  const int* __restrict__ slotJ,
                                  float* __restrict__ updSlot) {
    int b = blockIdx.x & 7;                      // batch -> XCD locality
    int e = (blockIdx.x >> 3) * blockDim.x + threadIdx.x;
    if (e >= kE) return;
    int4 ec = EC[e];
    int vi = ec.x, vj = ec.y;
    float initd = __int_as_float(ec.z);
    size_t vbase = (size_t)b * kN;

    const float* pi = Vp + (vbase + vi) * 3;
    const float* pj = Vp + (vbase + vj) * 3;
    float nx = pi[0] - pj[0];
    float ny = pi[1] - pj[1];
    float nz = pi[2] - pj[2];
    float D = sqrtf(nx * nx + ny * ny + nz * nz);
    float C = D - initd;

    size_t ebase = (size_t)b * kE + e;
    float2 as = AS[ebase];
    float Lold = L[ebase];
    float Ld = (-C - as.x * Lold) * as.y;
    L[ebase] = Lold + Ld;

    float ux = Ld * (nx / D);
    float uy = Ld * (ny / D);
    float uz = Ld * (nz / D);

    size_t sbase = (size_t)b * 2 * kE;
    float* ui = updSlot + (sbase + slotI[e]) * 3;
    ui[0] = ux;  ui[1] = uy;  ui[2] = uz;
    float* uj = updSlot + (sbase + slotJ[e]) * 3;
    uj[0] = -ux; uj[1] = -uy; uj[2] = -uz;
}

// Slot path phase 2: contiguous, coalesced gather of the slot range.
__global__ void apply_slot_kernel(const float* __restrict__ VpSrc,
                                  float* __restrict__ VpDst,
                                  const float* __restrict__ updSlot,
                                  const float* __restrict__ Vw,
                                  const int* __restrict__ start) {
    int b = blockIdx.x & 7;
    int v = (blockIdx.x >> 3) * blockDim.x + threadIdx.x;
    if (v >= kN) return;
    int s0 = start[v], s1 = start[v + 1];
    size_t sbase = (size_t)b * 2 * kE;
    float sx = 0.f, sy = 0.f, sz = 0.f;
    for (int k = s0; k < s1; ++k) {
        const float* u = updSlot + (sbase + k) * 3;
        sx += u[0]; sy += u[1]; sz += u[2];
    }
    size_t idx = (size_t)b * kN + v;
    float w = Vw[idx];
    const float* ps = VpSrc + idx * 3;
    float* pd = VpDst + idx * 3;
    pd[0] = ps[0] + w * sx;
    pd[1] = ps[1] + w * sy;
    pd[2] = ps[2] + w * sz;
}

// Fallback (smaller workspace): R2 per-edge upd + inc-based gather.
__global__ void solve_fb_kernel(const float* __restrict__ Vp,
                                float* __restrict__ L,
                                const float2* __restrict__ AS,
                                const float* __restrict__ Cinit,
                                const int* __restrict__ Cdist,
                                float* __restrict__ upd) {
    int b = blockIdx.x & 7;
    int e = (blockIdx.x >> 3) * blockDim.x + threadIdx.x;
    if (e >= kE) return;
    int vi = Cdist[2 * e + 0];
    int vj = Cdist[2 * e + 1];
    size_t vbase = (size_t)b * kN;
    const float* pi = Vp + (vbase + vi) * 3;
    const float* pj = Vp + (vbase + vj) * 3;
    float nx = pi[0] - pj[0];
    float ny = pi[1] - pj[1];
    float nz = pi[2] - pj[2];
    float D = sqrtf(nx * nx + ny * ny + nz * nz);
    float C = D - Cinit[e];
    size_t ebase = (size_t)b * kE + e;
    float2 as = AS[ebase];
    float Lold = L[ebase];
    float Ld = (-C - as.x * Lold) * as.y;
    L[ebase] = Lold + Ld;
    float* u = upd + ebase * 3;
    u[0] = Ld * (nx / D);
    u[1] = Ld * (ny / D);
    u[2] = Ld * (nz / D);
}

__global__ void apply_fb_kernel(const float* __restrict__ VpSrc,
                                float* __restrict__ VpDst,
                                const float* __restrict__ upd,
                                const float* __restrict__ Vw,
                                const int* __restrict__ start,
                                const int* __restrict__ inc) {
    int b = blockIdx.x & 7;
    int v = (blockIdx.x >> 3) * blockDim.x + threadIdx.x;
    if (v >= kN) return;
    int s0 = start[v], s1 = start[v + 1];
    float sx = 0.f, sy = 0.f, sz = 0.f;
    size_t ubase = (size_t)b * kE;
    for (int k = s0; k < s1; ++k) {
        int ic = inc[k];
        const float* u = upd + (ubase + (ic >> 1)) * 3;
        if (ic & 1) { sx -= u[0]; sy -= u[1]; sz -= u[2]; }
        else        { sx += u[0]; sy += u[1]; sz += u[2]; }
    }
    size_t idx = (size_t)b * kN + v;
    float w = Vw[idx];
    const float* ps = VpSrc + idx * 3;
    float* pd = VpDst + idx * 3;
    pd[0] = ps[0] + w * sx;
    pd[1] = ps[1] + w * sy;
    pd[2] = ps[2] + w * sz;
}

__global__ void finalize_kernel(const float* __restrict__ V,
                                const float* __restrict__ Vp,
                                float* __restrict__ outV,
                                float* __restrict__ outVel) {
    int idx = blockIdx.x * blockDim.x + threadIdx.x;
    if (idx >= kBN) return;
    int k = idx * 3;
    float vx = V[k], vy = V[k + 1], vz0 = V[k + 2];
    float px = Vp[k], py = Vp[k + 1], pz = Vp[k + 2];

    bool col = (pz < kH) && (vz0 > kH);
    float h_prev = vz0 - kH;
    float h_after = kH - pz;
    float denom = col ? (h_prev + h_after) : 1.0f;
    float t = h_prev / denom;

    float x  = col ? (vx + t * (px - vx)) : px;
    float y  = col ? (vy + t * (py - vy)) : py;
    float z1 = col ? (kH + kEps) : pz;

    bool vio = (z1 < kH) && (vz0 < kH);
    float z2 = vio ? (kH + kEps) : z1;

    float velx = (x  - vx ) / kDT;
    float vely = (y  - vy ) / kDT;
    float velz = (z2 - vz0) / kDT;
    velz = col ? -velz : velz;
    velz = vio ? 0.0f : velz;

    outV[k] = x;  outV[k + 1] = y;  outV[k + 2] = z2;
    outVel[k] = velx; outVel[k + 1] = vely; outVel[k + 2] = velz;
}

// ---------------- launch ----------------

extern "C" void kernel_launch(void* const* d_in, const int* in_sizes, int n_in,
                              void* d_out, int out_size, void* d_ws, size_t ws_size,
                              hipStream_t stream) {
    const float* V      = (const float*)d_in[0];
    const float* Vvel   = (const float*)d_in[1];
    const float* Vw     = (const float*)d_in[2];
    const float* Vcomp  = (const float*)d_in[3];
    const float* Vmass  = (const float*)d_in[4];
    const float* Vforce = (const float*)d_in[5];
    const float* Cinit  = (const float*)d_in[6];
    const int*   Cdist  = (const int*)d_in[7];

    char* p = (char*)d_ws;
    auto alloc = [&](size_t bytes) -> void* {
        p = (char*)(((uintptr_t)p + 15) & ~(uintptr_t)15);
        void* r = (void*)p;
        p += bytes;
        return r;
    };

    float*  VpA    = (float*)alloc((size_t)kBN * 3 * sizeof(float));
    float*  VpB    = (float*)alloc((size_t)kBN * 3 * sizeof(float));
    float*  L      = (float*)alloc((size_t)kBE * sizeof(float));
    float2* AS     = (float2*)alloc((size_t)kBE * sizeof(float2));
    int*    start  = (int*)alloc((size_t)(kN + 1) * sizeof(int));
    int*    cursor = (int*)alloc((size_t)kN * sizeof(int));
    int*    inc    = (int*)alloc((size_t)2 * kE * sizeof(int));
    int*    blkSum = (int*)alloc((size_t)kNB * sizeof(int));
    int*    blkOff = (int*)alloc((size_t)kNB * sizeof(int));
    char*   common_end = p;

    // slot-path extras
    float* updSlot = (float*)alloc((size_t)kB * 2 * kE * 3 * sizeof(float));
    int*   slotI   = (int*)alloc((size_t)kE * sizeof(int));
    int*   slotJ   = (int*)alloc((size_t)kE * sizeof(int));
    int4*  EC      = (int4*)alloc((size_t)kE * sizeof(int4));
    size_t needSlot = (size_t)(p - (char*)d_ws);
    bool useSlot = ws_size >= needSlot;

    // fallback extras (overlap the slot region)
    float* upd = (float*)common_end;   // kBE*3 floats

    const int TB = 256;
    dim3 blk(TB);
    dim3 gE((kE + TB - 1) / TB);
    dim3 gE8(((kE + TB - 1) / TB) * 8);
    dim3 gV8(((kN + TB - 1) / TB) * 8);
    dim3 gBN((kBN + TB - 1) / TB);
    dim3 g2E((2 * kE + TB - 1) / TB);

    // CSR build (cursor doubles as counts)
    hipMemsetAsync(cursor, 0, kN * sizeof(int), stream);
    count_kernel<<<gE, blk, 0, stream>>>(Cdist, cursor);
    partial_sum_kernel<<<dim3(kNB), blk, 0, stream>>>(cursor, blkSum);
    scan_sums_kernel<<<dim3(1), blk, 0, stream>>>(blkSum, blkOff);
    scatter_scan_kernel<<<dim3(kNB), blk, 0, stream>>>(cursor, blkOff, start);
    hipMemcpyAsync(cursor, start, kN * sizeof(int), hipMemcpyDeviceToDevice, stream);
    fill_kernel<<<gE, blk, 0, stream>>>(Cdist, cursor, inc);
    if (useSlot) {
        invert_kernel<<<g2E, blk, 0, stream>>>(inc, slotI, slotJ);
        ec_kernel<<<gE, blk, 0, stream>>>(Cdist, Cinit, EC);
    }

    // Invariants + prediction
    precompute_kernel<<<gE8, blk, 0, stream>>>(Cdist, Vw, Vcomp, AS);
    hipMemsetAsync(L, 0, (size_t)kBE * sizeof(float), stream);
    predict_kernel<<<gBN, blk, 0, stream>>>(V, Vvel, Vmass, Vforce, VpA);

    for (int it = 0; it < kIter; ++it) {
        float* src = (it & 1) ? VpB : VpA;
        float* dst = (it & 1) ? VpA : VpB;
        if (useSlot) {
            solve_slot_kernel<<<gE8, blk, 0, stream>>>(src, L, AS, EC, slotI, slotJ, updSlot);
            apply_slot_kernel<<<gV8, blk, 0, stream>>>(src, dst, updSlot, Vw, start);
        } else {
            solve_fb_kernel<<<gE8, blk, 0, stream>>>(src, L, AS, Cinit, Cdist, upd);
            apply_fb_kernel<<<gV8, blk, 0, stream>>>(src, dst, upd, Vw, start, inc);
        }
    }
    // 10 sweeps: final positions are back in VpA.
    float* outV   = (float*)d_out;
    float* outVel = outV + (size_t)kBN * 3;
    finalize_kernel<<<gBN, blk, 0, stream>>>(V, VpA, outV, outVel);
}

// Round 4
// 759.009 us; speedup vs baseline: 1.2151x; 1.2151x over previous
//
#include <hip/hip_runtime.h>
#include <math.h>
#include <stdint.h>

namespace {
constexpr float kDT  = 0.01f;   // DT / SUBSTEP, SUBSTEP == 1
constexpr int   kIter = 10;
constexpr float kH   = -2.0f;
constexpr float kEps = 1e-5f;
constexpr int   kB = 8;
constexpr int   kN = 50000;
constexpr int   kE = 200000;
constexpr int   kBN = kB * kN;
constexpr int   kNB = (kN + 255) / 256;   // blocks for per-vertex scan
}

// ---------------- CSR build (once per launch) ----------------

__global__ void count_kernel(const int2* __restrict__ Cdist, int* __restrict__ counts) {
    int e = blockIdx.x * blockDim.x + threadIdx.x;
    if (e >= kE) return;
    int2 c = Cdist[e];
    atomicAdd(&counts[c.x], 1);
    atomicAdd(&counts[c.y], 1);
}

__global__ void partial_sum_kernel(const int* __restrict__ counts, int* __restrict__ blkSum) {
    __shared__ int s[256];
    int i = blockIdx.x * 256 + threadIdx.x;
    s[threadIdx.x] = (i < kN) ? counts[i] : 0;
    __syncthreads();
    for (int off = 128; off > 0; off >>= 1) {
        if (threadIdx.x < off) s[threadIdx.x] += s[threadIdx.x + off];
        __syncthreads();
    }
    if (threadIdx.x == 0) blkSum[blockIdx.x] = s[0];
}

__global__ void scan_sums_kernel(const int* __restrict__ blkSum, int* __restrict__ blkOff) {
    __shared__ int s[kNB];
    int tid = threadIdx.x;                 // 256 threads >= kNB
    if (tid < kNB) s[tid] = blkSum[tid];
    __syncthreads();
    if (tid == 0) {
        int acc = 0;
        for (int i = 0; i < kNB; ++i) { int v = s[i]; s[i] = acc; acc += v; }
    }
    __syncthreads();
    if (tid < kNB) blkOff[tid] = s[tid];
}

__global__ void scatter_scan_kernel(const int* __restrict__ counts,
                                    const int* __restrict__ blkOff,
                                    int* __restrict__ start) {
    __shared__ int s[256];
    int tid = threadIdx.x;
    int i = blockIdx.x * 256 + tid;
    int c = (i < kN) ? counts[i] : 0;
    s[tid] = c;
    __syncthreads();
    for (int off = 1; off < 256; off <<= 1) {      // inclusive Hillis-Steele
        int v = (tid >= off) ? s[tid - off] : 0;
        __syncthreads();
        s[tid] += v;
        __syncthreads();
    }
    int incl = s[tid];
    int excl = incl - c;
    if (i < kN) start[i] = blkOff[blockIdx.x] + excl;
    if (i == kN - 1) start[kN] = blkOff[blockIdx.x] + incl;   // == 2E
}

// inc id = 2*e + side. Fill order nondeterministic (atomics); summation-order
// FP wiggle is far below the 2% tolerance (validated R1-R3).
__global__ void fill_kernel(const int2* __restrict__ Cdist, int* __restrict__ cursor,
                            int* __restrict__ inc) {
    int e = blockIdx.x * blockDim.x + threadIdx.x;
    if (e >= kE) return;
    int2 c = Cdist[e];
    int p0 = atomicAdd(&cursor[c.x], 1);
    inc[p0] = 2 * e;
    int p1 = atomicAdd(&cursor[c.y], 1);
    inc[p1] = 2 * e + 1;
}

// Per-slot static data: {other endpoint, init_d bits}
__global__ void ss_build_kernel(const int* __restrict__ inc,
                                const int2* __restrict__ Cdist,
                                const float* __restrict__ Cinit,
                                int2* __restrict__ SS) {
    int k = blockIdx.x * blockDim.x + threadIdx.x;
    if (k >= 2 * kE) return;
    int ic = inc[k];
    int e = ic >> 1;
    int2 c = Cdist[e];
    int other = (ic & 1) ? c.x : c.y;
    SS[k] = make_int2(other, __float_as_int(Cinit[e]));
}

// ---------------- physics ----------------

// Vp4 = {x,y,z predicted, w}   (w rides in the spare lane for the sweep gather)
__global__ void predict_kernel(const float* __restrict__ V,
                               const float* __restrict__ Vvel,
                               const float* __restrict__ Vw,
                               const float* __restrict__ Vmass,
                               const float* __restrict__ Vforce,
                               float4* __restrict__ Vp4) {
    int idx = blockIdx.x * blockDim.x + threadIdx.x;
    if (idx >= kBN) return;
    float m = Vmass[idx];
    float4 r;
    {
        int k = idx * 3;
        float vpx = Vvel[k + 0] + (kDT * Vforce[k + 0]) / m;   // (dt*F)/m, reference order
        float vpy = Vvel[k + 1] + (kDT * Vforce[k + 1]) / m;
        float vpz = Vvel[k + 2] + (kDT * Vforce[k + 2]) / m;
        r.x = V[k + 0] + kDT * vpx;
        r.y = V[k + 1] + kDT * vpy;
        r.z = V[k + 2] + kDT * vpz;
    }
    r.w = Vw[idx];
    Vp4[idx] = r;
}

// One fused Jacobi sweep: each vertex recomputes its incident edges' corrections.
// Ld is bitwise identical from both endpoints (sign cancels in the squares; adds
// are commutative), so per-slot duplicated L copies evolve identically.
__global__ void sweep_kernel(const float4* __restrict__ Vp4Src,
                             float4* __restrict__ Vp4Dst,
                             const float* __restrict__ Lsrc,
                             float* __restrict__ Ldst,
                             const int2* __restrict__ SS,
                             const float* __restrict__ Vcomp,
                             const int* __restrict__ start) {
    int b = blockIdx.x & 7;                       // batch -> XCD locality
    int v = (blockIdx.x >> 3) * blockDim.x + threadIdx.x;
    if (v >= kN) return;
    size_t vb = (size_t)b * kN;
    float4 own = Vp4Src[vb + v];
    float comp_own = Vcomp[vb + v];
    int s0 = start[v], s1 = start[v + 1];
    size_t lb = (size_t)b * (2 * kE);
    float sx = 0.f, sy = 0.f, sz = 0.f;
    for (int k = s0; k < s1; ++k) {
        int2 ss = SS[k];
        float4 oth = Vp4Src[vb + ss.x];           // 16B aligned gather (L2)
        float Lold = Lsrc[lb + k];                // coalesced-ish stream
        float dx = own.x - oth.x;
        float dy = own.y - oth.y;
        float dz = own.z - oth.z;
        float D = sqrtf(dx * dx + dy * dy + dz * dz);
        float C = D - __int_as_float(ss.y);
        float A = (comp_own + Vcomp[vb + ss.x]) * 0.5f;
        float S = own.w + oth.w;
        if (S == 0.0f) S = INFINITY;
        float Ld = (-C - A * Lold) / (S + A);
        Ldst[lb + k] = Lold + Ld;
        float rD = 1.0f / D;
        sx += Ld * (dx * rD);
        sy += Ld * (dy * rD);
        sz += Ld * (dz * rD);
    }
    float4 r;
    r.x = own.x + own.w * sx;
    r.y = own.y + own.w * sy;
    r.z = own.z + own.w * sz;
    r.w = own.w;
    Vp4Dst[vb + v] = r;
}

__global__ void finalize_kernel(const float* __restrict__ V,
                                const float4* __restrict__ Vp4,
                                float* __restrict__ outV,
                                float* __restrict__ outVel) {
    int idx = blockIdx.x * blockDim.x + threadIdx.x;
    if (idx >= kBN) return;
    int k = idx * 3;
    float vx = V[k], vy = V[k + 1], vz0 = V[k + 2];
    float4 p = Vp4[idx];
    float px = p.x, py = p.y, pz = p.z;

    bool col = (pz < kH) && (vz0 > kH);
    float h_prev = vz0 - kH;
    float h_after = kH - pz;
    float denom = col ? (h_prev + h_after) : 1.0f;
    float t = h_prev / denom;

    float x  = col ? (vx + t * (px - vx)) : px;
    float y  = col ? (vy + t * (py - vy)) : py;
    float z1 = col ? (kH + kEps) : pz;

    bool vio = (z1 < kH) && (vz0 < kH);
    float z2 = vio ? (kH + kEps) : z1;

    float velx = (x  - vx ) / kDT;
    float vely = (y  - vy ) / kDT;
    float velz = (z2 - vz0) / kDT;
    velz = col ? -velz : velz;
    velz = vio ? 0.0f : velz;

    outV[k] = x;  outV[k + 1] = y;  outV[k + 2] = z2;
    outVel[k] = velx; outVel[k + 1] = vely; outVel[k + 2] = velz;
}

// ---------------- launch ----------------

extern "C" void kernel_launch(void* const* d_in, const int* in_sizes, int n_in,
                              void* d_out, int out_size, void* d_ws, size_t ws_size,
                              hipStream_t stream) {
    const float* V      = (const float*)d_in[0];
    const float* Vvel   = (const float*)d_in[1];
    const float* Vw     = (const float*)d_in[2];
    const float* Vcomp  = (const float*)d_in[3];
    const float* Vmass  = (const float*)d_in[4];
    const float* Vforce = (const float*)d_in[5];
    const float* Cinit  = (const float*)d_in[6];
    const int2*  Cdist  = (const int2*)d_in[7];

    char* p = (char*)d_ws;
    auto alloc = [&](size_t bytes) -> void* {
        p = (char*)(((uintptr_t)p + 15) & ~(uintptr_t)15);
        void* r = (void*)p;
        p += bytes;
        return r;
    };

    float4* Vp4A   = (float4*)alloc((size_t)kBN * sizeof(float4));          // 6.4 MB
    float4* Vp4B   = (float4*)alloc((size_t)kBN * sizeof(float4));          // 6.4 MB
    float*  LA     = (float*)alloc((size_t)kB * 2 * kE * sizeof(float));    // 12.8 MB
    float*  LB     = (float*)alloc((size_t)kB * 2 * kE * sizeof(float));    // 12.8 MB
    int2*   SS     = (int2*)alloc((size_t)2 * kE * sizeof(int2));           // 3.2 MB
    int*    start  = (int*)alloc((size_t)(kN + 1) * sizeof(int));
    int*    cursor = (int*)alloc((size_t)kN * sizeof(int));
    int*    inc    = (int*)alloc((size_t)2 * kE * sizeof(int));
    int*    blkSum = (int*)alloc((size_t)kNB * sizeof(int));
    int*    blkOff = (int*)alloc((size_t)kNB * sizeof(int));

    const int TB = 256;
    dim3 blk(TB);
    dim3 gE((kE + TB - 1) / TB);
    dim3 g2E((2 * kE + TB - 1) / TB);
    dim3 gV8(((kN + TB - 1) / TB) * 8);
    dim3 gBN((kBN + TB - 1) / TB);

    // CSR build (cursor doubles as counts)
    hipMemsetAsync(cursor, 0, kN * sizeof(int), stream);
    count_kernel<<<gE, blk, 0, stream>>>(Cdist, cursor);
    partial_sum_kernel<<<dim3(kNB), blk, 0, stream>>>(cursor, blkSum);
    scan_sums_kernel<<<dim3(1), blk, 0, stream>>>(blkSum, blkOff);
    scatter_scan_kernel<<<dim3(kNB), blk, 0, stream>>>(cursor, blkOff, start);
    hipMemcpyAsync(cursor, start, kN * sizeof(int), hipMemcpyDeviceToDevice, stream);
    fill_kernel<<<gE, blk, 0, stream>>>(Cdist, cursor, inc);
    ss_build_kernel<<<g2E, blk, 0, stream>>>(inc, Cdist, Cinit, SS);

    // L init + prediction
    hipMemsetAsync(LA, 0, (size_t)kB * 2 * kE * sizeof(float), stream);
    predict_kernel<<<gBN, blk, 0, stream>>>(V, Vvel, Vw, Vmass, Vforce, Vp4A);

    for (int it = 0; it < kIter; ++it) {
        float4* src = (it & 1) ? Vp4B : Vp4A;
        float4* dst = (it & 1) ? Vp4A : Vp4B;
        float*  ls  = (it & 1) ? LB : LA;
        float*  ld  = (it & 1) ? LA : LB;
        sweep_kernel<<<gV8, blk, 0, stream>>>(src, dst, ls, ld, SS, Vcomp, start);
    }
    // 10 sweeps: final positions are back in Vp4A.
    float* outV   = (float*)d_out;
    float* outVel = outV + (size_t)kBN * 3;
    finalize_kernel<<<gBN, blk, 0, stream>>>(V, Vp4A, outV, outVel);
}

// Round 5
// 392.670 us; speedup vs baseline: 2.3488x; 1.9329x over previous
//
#include <hip/hip_runtime.h>
#include <math.h>
#include <stdint.h>

namespace {
constexpr float kDT  = 0.01f;   // DT / SUBSTEP, SUBSTEP == 1
constexpr int   kIter = 10;
constexpr float kH   = -2.0f;
constexpr float kEps = 1e-5f;
constexpr int   kB = 8;
constexpr int   kN = 50000;
constexpr int   kE = 200000;
constexpr int   kBN = kB * kN;
constexpr int   kNB = (kN + 255) / 256;   // blocks for per-vertex scan
}

// ---------------- CSR build (once per launch) ----------------

__global__ void count_kernel(const int2* __restrict__ Cdist, int* __restrict__ counts) {
    int e = blockIdx.x * blockDim.x + threadIdx.x;
    if (e >= kE) return;
    int2 c = Cdist[e];
    atomicAdd(&counts[c.x], 1);
    atomicAdd(&counts[c.y], 1);
}

__global__ void partial_sum_kernel(const int* __restrict__ counts, int* __restrict__ blkSum) {
    __shared__ int s[256];
    int i = blockIdx.x * 256 + threadIdx.x;
    s[threadIdx.x] = (i < kN) ? counts[i] : 0;
    __syncthreads();
    for (int off = 128; off > 0; off >>= 1) {
        if (threadIdx.x < off) s[threadIdx.x] += s[threadIdx.x + off];
        __syncthreads();
    }
    if (threadIdx.x == 0) blkSum[blockIdx.x] = s[0];
}

__global__ void scan_sums_kernel(const int* __restrict__ blkSum, int* __restrict__ blkOff) {
    __shared__ int s[kNB];
    int tid = threadIdx.x;                 // 256 threads >= kNB
    if (tid < kNB) s[tid] = blkSum[tid];
    __syncthreads();
    if (tid == 0) {
        int acc = 0;
        for (int i = 0; i < kNB; ++i) { int v = s[i]; s[i] = acc; acc += v; }
    }
    __syncthreads();
    if (tid < kNB) blkOff[tid] = s[tid];
}

__global__ void scatter_scan_kernel(const int* __restrict__ counts,
                                    const int* __restrict__ blkOff,
                                    int* __restrict__ start) {
    __shared__ int s[256];
    int tid = threadIdx.x;
    int i = blockIdx.x * 256 + tid;
    int c = (i < kN) ? counts[i] : 0;
    s[tid] = c;
    __syncthreads();
    for (int off = 1; off < 256; off <<= 1) {      // inclusive Hillis-Steele
        int v = (tid >= off) ? s[tid - off] : 0;
        __syncthreads();
        s[tid] += v;
        __syncthreads();
    }
    int incl = s[tid];
    int excl = incl - c;
    if (i < kN) start[i] = blkOff[blockIdx.x] + excl;
    if (i == kN - 1) start[kN] = blkOff[blockIdx.x] + incl;   // == 2E
}

// inc id = 2*e + side. Fill order nondeterministic (atomics); summation-order
// FP wiggle is far below the tolerance (validated R1-R4).
__global__ void fill_kernel(const int2* __restrict__ Cdist, int* __restrict__ cursor,
                            int* __restrict__ inc) {
    int e = blockIdx.x * blockDim.x + threadIdx.x;
    if (e >= kE) return;
    int2 c = Cdist[e];
    int p0 = atomicAdd(&cursor[c.x], 1);
    inc[p0] = 2 * e;
    int p1 = atomicAdd(&cursor[c.y], 1);
    inc[p1] = 2 * e + 1;
}

// ---------------- predict + batch-minor re-layout ----------------

// P[v][b] = {x,y,z predicted, w};  WC[v][b] = {w, comp}
__global__ void predict_kernel(const float* __restrict__ V,
                               const float* __restrict__ Vvel,
                               const float* __restrict__ Vw,
                               const float* __restrict__ Vcomp,
                               const float* __restrict__ Vmass,
                               const float* __restrict__ Vforce,
                               float4* __restrict__ P,
                               float2* __restrict__ WC) {
    int v = blockIdx.x * blockDim.x + threadIdx.x;
    if (v >= kN) return;
#pragma unroll
    for (int b = 0; b < kB; ++b) {
        int idx = b * kN + v;
        int k = idx * 3;
        float m = Vmass[idx];
        float4 r;
        float vpx = Vvel[k + 0] + (kDT * Vforce[k + 0]) / m;   // (dt*F)/m, reference order
        float vpy = Vvel[k + 1] + (kDT * Vforce[k + 1]) / m;
        float vpz = Vvel[k + 2] + (kDT * Vforce[k + 2]) / m;
        float w = Vw[idx];
        r.x = V[k + 0] + kDT * vpx;
        r.y = V[k + 1] + kDT * vpy;
        r.z = V[k + 2] + kDT * vpz;
        r.w = w;
        P[v * 8 + b] = r;
        WC[v * 8 + b] = make_float2(w, Vcomp[idx]);
    }
}

// Per-slot static data: SS[k] = {other, init_d bits}; ASrec[k][b] = {A, 1/(S+A)}
__global__ void slots_build_kernel(const int* __restrict__ inc,
                                   const int2* __restrict__ Cdist,
                                   const float* __restrict__ Cinit,
                                   const float2* __restrict__ WC,
                                   int2* __restrict__ SS,
                                   float2* __restrict__ ASrec) {
    int k = blockIdx.x * blockDim.x + threadIdx.x;
    if (k >= 2 * kE) return;
    int ic = inc[k];
    int e = ic >> 1;
    int2 c = Cdist[e];
    int other = (ic & 1) ? c.x : c.y;
    SS[k] = make_int2(other, __float_as_int(Cinit[e]));
#pragma unroll
    for (int b = 0; b < kB; ++b) {
        float2 wi = WC[c.x * 8 + b];
        float2 wj = WC[c.y * 8 + b];
        float A = (wi.y + wj.y) * 0.5f;
        float S = wi.x + wj.x;
        if (S == 0.0f) S = INFINITY;
        ASrec[k * 8 + b] = make_float2(A, 1.0f / (S + A));
    }
}

// ---------------- fused Jacobi sweep ----------------
// Thread = (vertex v, batch-group bg of 4). Each vertex recomputes its incident
// edges' corrections (Ld bitwise-identical from either endpoint), so no
// edge->vertex communication. L[slot][b] is owned by exactly one thread ->
// safe in-place update. Neighbor gather = one aligned 64B line per (slot,bg).
__global__ void sweep_kernel(const float4* __restrict__ Psrc,
                             float4* __restrict__ Pdst,
                             float* __restrict__ L,
                             const int2* __restrict__ SS,
                             const float2* __restrict__ ASrec,
                             const int* __restrict__ start) {
    int t = blockIdx.x * blockDim.x + threadIdx.x;
    if (t >= 2 * kN) return;
    int v = t >> 1;
    int off = (t & 1) * 4;

    float4 own[4];
#pragma unroll
    for (int j = 0; j < 4; ++j) own[j] = Psrc[v * 8 + off + j];
    float ax[4] = {0.f, 0.f, 0.f, 0.f};
    float ay[4] = {0.f, 0.f, 0.f, 0.f};
    float az[4] = {0.f, 0.f, 0.f, 0.f};

    int s0 = start[v], s1 = start[v + 1];
    for (int k = s0; k < s1; ++k) {
        int2 ss = SS[k];
        float initd = __int_as_float(ss.y);
        const float4* po = Psrc + (size_t)ss.x * 8 + off;   // one 64B line
        const float2* as = ASrec + (size_t)k * 8 + off;
        float* lp = L + (size_t)k * 8 + off;
#pragma unroll
        for (int j = 0; j < 4; ++j) {
            float4 oth = po[j];
            float dx = own[j].x - oth.x;
            float dy = own[j].y - oth.y;
            float dz = own[j].z - oth.z;
            float D = sqrtf(dx * dx + dy * dy + dz * dz);
            float C = D - initd;
            float2 a = as[j];
            float Lold = lp[j];
            float Ld = (-C - a.x * Lold) * a.y;
            lp[j] = Lold + Ld;
            float rD = 1.0f / D;
            ax[j] += Ld * (dx * rD);
            ay[j] += Ld * (dy * rD);
            az[j] += Ld * (dz * rD);
        }
    }
#pragma unroll
    for (int j = 0; j < 4; ++j) {
        float4 r;
        r.x = own[j].x + own[j].w * ax[j];
        r.y = own[j].y + own[j].w * ay[j];
        r.z = own[j].z + own[j].w * az[j];
        r.w = own[j].w;
        Pdst[v * 8 + off + j] = r;
    }
}

// ---------------- finalize ----------------

__global__ void finalize_kernel(const float* __restrict__ V,
                                const float4* __restrict__ P,
                                float* __restrict__ outV,
                                float* __restrict__ outVel) {
    int v = blockIdx.x * blockDim.x + threadIdx.x;
    if (v >= kN) return;
#pragma unroll
    for (int b = 0; b < kB; ++b) {
        int k = (b * kN + v) * 3;
        float vx = V[k], vy = V[k + 1], vz0 = V[k + 2];
        float4 p = P[v * 8 + b];
        float px = p.x, py = p.y, pz = p.z;

        bool col = (pz < kH) && (vz0 > kH);
        float h_prev = vz0 - kH;
        float h_after = kH - pz;
        float denom = col ? (h_prev + h_after) : 1.0f;
        float t = h_prev / denom;

        float x  = col ? (vx + t * (px - vx)) : px;
        float y  = col ? (vy + t * (py - vy)) : py;
        float z1 = col ? (kH + kEps) : pz;

        bool vio = (z1 < kH) && (vz0 < kH);
        float z2 = vio ? (kH + kEps) : z1;

        float velx = (x  - vx ) / kDT;
        float vely = (y  - vy ) / kDT;
        float velz = (z2 - vz0) / kDT;
        velz = col ? -velz : velz;
        velz = vio ? 0.0f : velz;

        outV[k] = x;  outV[k + 1] = y;  outV[k + 2] = z2;
        outVel[k] = velx; outVel[k + 1] = vely; outVel[k + 2] = velz;
    }
}

// ---------------- launch ----------------

extern "C" void kernel_launch(void* const* d_in, const int* in_sizes, int n_in,
                              void* d_out, int out_size, void* d_ws, size_t ws_size,
                              hipStream_t stream) {
    const float* V      = (const float*)d_in[0];
    const float* Vvel   = (const float*)d_in[1];
    const float* Vw     = (const float*)d_in[2];
    const float* Vcomp  = (const float*)d_in[3];
    const float* Vmass  = (const float*)d_in[4];
    const float* Vforce = (const float*)d_in[5];
    const float* Cinit  = (const float*)d_in[6];
    const int2*  Cdist  = (const int2*)d_in[7];

    char* p = (char*)d_ws;
    auto alloc = [&](size_t bytes) -> void* {
        p = (char*)(((uintptr_t)p + 255) & ~(uintptr_t)255);
        void* r = (void*)p;
        p += bytes;
        return r;
    };

    float4* PA     = (float4*)alloc((size_t)kN * 8 * sizeof(float4));       // 6.4 MB
    float4* PB     = (float4*)alloc((size_t)kN * 8 * sizeof(float4));       // 6.4 MB
    float*  L      = (float*)alloc((size_t)2 * kE * 8 * sizeof(float));     // 12.8 MB
    float2* ASrec  = (float2*)alloc((size_t)2 * kE * 8 * sizeof(float2));   // 25.6 MB
    int2*   SS     = (int2*)alloc((size_t)2 * kE * sizeof(int2));           // 3.2 MB
    float2* WC     = (float2*)alloc((size_t)kN * 8 * sizeof(float2));       // 3.2 MB
    int*    start  = (int*)alloc((size_t)(kN + 1) * sizeof(int));
    int*    cursor = (int*)alloc((size_t)kN * sizeof(int));
    int*    inc    = (int*)alloc((size_t)2 * kE * sizeof(int));
    int*    blkSum = (int*)alloc((size_t)kNB * sizeof(int));
    int*    blkOff = (int*)alloc((size_t)kNB * sizeof(int));

    const int TB = 256;
    dim3 blk(TB);
    dim3 gE((kE + TB - 1) / TB);
    dim3 g2E((2 * kE + TB - 1) / TB);
    dim3 gN((kN + TB - 1) / TB);
    dim3 g2N((2 * kN + TB - 1) / TB);

    // CSR build (cursor doubles as counts)
    hipMemsetAsync(cursor, 0, kN * sizeof(int), stream);
    count_kernel<<<gE, blk, 0, stream>>>(Cdist, cursor);
    partial_sum_kernel<<<dim3(kNB), blk, 0, stream>>>(cursor, blkSum);
    scan_sums_kernel<<<dim3(1), blk, 0, stream>>>(blkSum, blkOff);
    scatter_scan_kernel<<<dim3(kNB), blk, 0, stream>>>(cursor, blkOff, start);
    hipMemcpyAsync(cursor, start, kN * sizeof(int), hipMemcpyDeviceToDevice, stream);
    fill_kernel<<<gE, blk, 0, stream>>>(Cdist, cursor, inc);

    // predict + batch-minor layout, then per-slot invariants
    predict_kernel<<<gN, blk, 0, stream>>>(V, Vvel, Vw, Vcomp, Vmass, Vforce, PA, WC);
    slots_build_kernel<<<g2E, blk, 0, stream>>>(inc, Cdist, Cinit, WC, SS, ASrec);
    hipMemsetAsync(L, 0, (size_t)2 * kE * 8 * sizeof(float), stream);

    for (int it = 0; it < kIter; ++it) {
        float4* src = (it & 1) ? PB : PA;
        float4* dst = (it & 1) ? PA : PB;
        sweep_kernel<<<g2N, blk, 0, stream>>>(src, dst, L, SS, ASrec, start);
    }
    // 10 sweeps: final positions are back in PA.
    float* outV   = (float*)d_out;
    float* outVel = outV + (size_t)kBN * 3;
    finalize_kernel<<<gN, blk, 0, stream>>>(V, PA, outV, outVel);
}